// Round 1
// baseline (990.300 us; speedup 1.0000x reference)
//
#include <hip/hip_runtime.h>
#include <math.h>

#define B 4
#define H 256
#define W 256
#define HW 65536
#define LSTEPS 10
#define NCH 100
#define NG 8          // channel groups for resblock
#define KS 51
#define KR 25

// ---------------- init: copy source->images[0], broadcast z0->residuals[0], gauss weights
__global__ void init_kernel(const float* __restrict__ src, const float* __restrict__ z0,
                            float* __restrict__ images0, float* __restrict__ res0,
                            float* __restrict__ gw) {
    int tid = blockIdx.x * 256 + threadIdx.x;   // 0 .. B*HW-1
    images0[tid] = src[tid];
    res0[tid] = z0[tid & (HW - 1)];
    if (blockIdx.x == 0 && threadIdx.x == 0) {
        float e[KS];
        float s = 0.f;
        for (int k = 0; k < KS; k++) {
            float x = (float)(k - KR) / 6.0f;
            e[k] = expf(-0.5f * x * x);
            s += e[k];
        }
        for (int k = 0; k < KS; k++) gw[k] = e[k] / s;
    }
}

// ---------------- sobel gradient (edge clamp) + write grads + t = -z*g
__global__ void grad_mul_kernel(const float* __restrict__ img, const float* __restrict__ z,
                                float* __restrict__ grads_i, float* __restrict__ t) {
    int tid = blockIdx.x * 256 + threadIdx.x;   // 0 .. B*HW-1
    int b = tid >> 16;
    int p = tid & (HW - 1);
    int y = p >> 8, x = p & 255;
    const float* im = img + (b << 16);
    int ym = max(y - 1, 0), yp = min(y + 1, 255);
    int xm = max(x - 1, 0), xp = min(x + 1, 255);
    float a00 = im[ym * W + xm], a01 = im[ym * W + x], a02 = im[ym * W + xp];
    float a10 = im[y * W + xm],                         a12 = im[y * W + xp];
    float a20 = im[yp * W + xm], a21 = im[yp * W + x], a22 = im[yp * W + xp];
    float gx = ((a02 + 2.f * a12 + a22) - (a00 + 2.f * a10 + a20)) * 0.125f;
    float gy = ((a20 + 2.f * a21 + a22) - (a00 + 2.f * a01 + a02)) * 0.125f;
    grads_i[(b * 2 + 0) * HW + p] = gx;
    grads_i[(b * 2 + 1) * HW + p] = gy;
    float zz = z[tid];
    t[(b * 2 + 0) * HW + p] = -zz * gx;
    t[(b * 2 + 1) * HW + p] = -zz * gy;
}

// ---------------- vertical 51-tap blur (zero pad). grid: B*2*(W/32), 256 thr
#define VBC 32
__global__ void vblur_kernel(const float* __restrict__ t, const float* __restrict__ gw,
                             float* __restrict__ t2) {
    int bc = blockIdx.x / (W / VBC);     // b*2+ch
    int ct = blockIdx.x % (W / VBC);
    int col0 = ct * VBC;
    __shared__ float s[(H + 2 * KR) * VBC];
    const float* src = t + bc * HW + col0;
    for (int idx = threadIdx.x; idx < (H + 2 * KR) * VBC; idx += 256) {
        int r = idx / VBC, c = idx % VBC;
        int row = r - KR;
        s[idx] = (row >= 0 && row < H) ? src[row * W + c] : 0.f;
    }
    __syncthreads();
    int c = threadIdx.x & (VBC - 1);
    int r0 = (threadIdx.x >> 5) * 32;    // 8 segments of 32 rows
    float* dst = t2 + bc * HW + col0;
    for (int j = 0; j < 32; j++) {
        int row = r0 + j;
        float acc = 0.f;
#pragma unroll
        for (int k = 0; k < KS; k++) acc += gw[k] * s[(row + k) * VBC + c];
        dst[row * W + c] = acc;
    }
}

// ---------------- horizontal 51-tap blur + interleaved fields write. grid: B*H, 256 thr
__global__ void hblur_kernel(const float* __restrict__ t2, const float* __restrict__ gw,
                             float* __restrict__ fields_i) {
    int b = blockIdx.x >> 8;
    int row = blockIdx.x & 255;
    __shared__ float s0[W + 2 * KR], s1[W + 2 * KR];
    const float* r0 = t2 + (b * 2 + 0) * HW + row * W;
    const float* r1 = t2 + (b * 2 + 1) * HW + row * W;
    for (int idx = threadIdx.x; idx < W + 2 * KR; idx += 256) {
        int xx = idx - KR;
        bool ok = (xx >= 0 && xx < W);
        s0[idx] = ok ? r0[xx] : 0.f;
        s1[idx] = ok ? r1[xx] : 0.f;
    }
    __syncthreads();
    int x = threadIdx.x;
    float a0 = 0.f, a1 = 0.f;
#pragma unroll
    for (int k = 0; k < KS; k++) {
        float wk = gw[k];
        a0 += wk * s0[x + k];
        a1 += wk * s1[x + k];
    }
    float2* dst = (float2*)(fields_i + (size_t)(b * HW + row * W + x) * 2);
    *dst = make_float2(a0, a1);
}

// ---------------- fused resblock: conv3x3(2->100)+leaky+conv3x3(100->1), partial over channel group
// grid: NG*B*16 blocks, 256 threads; per-thread 4x4 outputs, 64x64 tile per block
__global__ __launch_bounds__(256, 2) void resblock_kernel(
        const float* __restrict__ z, const float* __restrict__ img,
        const float* __restrict__ w1, const float* __restrict__ b1,
        const float* __restrict__ w2, float* __restrict__ partial) {
    int bid = blockIdx.x;
    int tile = bid & 15;
    int b = (bid >> 4) & 3;
    int g = bid >> 6;
    int tx = tile & 3, ty = tile >> 2;
    int tid = threadIdx.x;
    int tcol = tid & 15, trow = tid >> 4;
    int ox = tx * 64 + tcol * 4;
    int oy = ty * 64 + trow * 4;
    const float* zp = z + (b << 16);
    const float* ip = img + (b << 16);

    // 8x8x2 input patch in registers, zero outside image (conv1 zero-pad)
    float inz[8][8], ini[8][8];
#pragma unroll
    for (int r = 0; r < 8; r++) {
        int y = oy - 2 + r;
        bool yok = ((unsigned)y < (unsigned)H);
#pragma unroll
        for (int c = 0; c < 8; c++) {
            int x = ox - 2 + c;
            bool ok = yok && ((unsigned)x < (unsigned)W);
            int idx = y * W + x;
            inz[r][c] = ok ? zp[idx] : 0.f;
            ini[r][c] = ok ? ip[idx] : 0.f;
        }
    }
    // hidden-position validity masks (conv2 sees ZERO outside [0,255], not conv1(bias))
    float mrow[6], mcol[6];
#pragma unroll
    for (int k = 0; k < 6; k++) {
        mrow[k] = ((unsigned)(oy - 1 + k) < (unsigned)H) ? 1.f : 0.f;
        mcol[k] = ((unsigned)(ox - 1 + k) < (unsigned)W) ? 1.f : 0.f;
    }

    float acc[4][4];
#pragma unroll
    for (int p = 0; p < 4; p++)
#pragma unroll
        for (int q = 0; q < 4; q++) acc[p][q] = 0.f;

    int c0 = (g < 4) ? g * 13 : 52 + (g - 4) * 12;
    int c1 = (g < 4) ? c0 + 13 : c0 + 12;

    for (int c = c0; c < c1; c++) {
        const float* w1c = w1 + c * 18;
        const float* w2c = w2 + c * 9;
        float bias = b1[c];
        float wz[9], wi[9], v2[9];
#pragma unroll
        for (int k = 0; k < 9; k++) {
            wz[k] = w1c[k];
            wi[k] = w1c[9 + k];
            v2[k] = w2c[k];
        }
        float h[6][6];
#pragma unroll
        for (int hr = 0; hr < 6; hr++) {
#pragma unroll
            for (int hc = 0; hc < 6; hc++) {
                float a = bias;
#pragma unroll
                for (int ky = 0; ky < 3; ky++) {
#pragma unroll
                    for (int kx = 0; kx < 3; kx++) {
                        a += wz[ky * 3 + kx] * inz[hr + ky][hc + kx];
                        a += wi[ky * 3 + kx] * ini[hr + ky][hc + kx];
                    }
                }
                float l = fmaxf(a, 0.01f * a);        // leaky relu (slope<1)
                h[hr][hc] = l * mrow[hr] * mcol[hc];  // mask invalid hidden positions
            }
        }
#pragma unroll
        for (int p = 0; p < 4; p++) {
#pragma unroll
            for (int q = 0; q < 4; q++) {
                float a = acc[p][q];
#pragma unroll
                for (int ky = 0; ky < 3; ky++) {
#pragma unroll
                    for (int kx = 0; kx < 3; kx++)
                        a += v2[ky * 3 + kx] * h[p + ky][q + kx];
                }
                acc[p][q] = a;
            }
        }
    }
    float* dst = partial + (size_t)(g * B + b) * HW;
#pragma unroll
    for (int p = 0; p < 4; p++)
#pragma unroll
        for (int q = 0; q < 4; q++)
            dst[(oy + p) * W + ox + q] = acc[p][q];
}

// ---------------- finalize resblock partials -> z_next, bilinear deform, image update
__global__ void deform_kernel(const float* __restrict__ img, const float* __restrict__ z,
                              const float* __restrict__ fields_i, const float* __restrict__ partial,
                              float* __restrict__ res_next, float* __restrict__ img_next) {
    int tid = blockIdx.x * 256 + threadIdx.x;   // 0 .. B*HW-1
    int b = tid >> 16;
    int p = tid & (HW - 1);
    int y = p >> 8, x = p & 255;
    float f = 0.f;
#pragma unroll
    for (int g = 0; g < NG; g++) f += partial[(size_t)(g * B + b) * HW + p];
    float zn = z[tid] + f / 10.0f;
    res_next[tid] = zn;
    float2 fv = *(const float2*)(fields_i + (size_t)tid * 2);
    float sx = (float)x - fv.x / 10.0f;
    float sy = (float)y - fv.y / 10.0f;
    float x0f = floorf(sx), y0f = floorf(sy);
    float wx = sx - x0f, wy = sy - y0f;
    int ix0 = min(max((int)x0f, 0), W - 1);
    int ix1 = min(max((int)x0f + 1, 0), W - 1);
    int iy0 = min(max((int)y0f, 0), H - 1);
    int iy1 = min(max((int)y0f + 1, 0), H - 1);
    const float* im = img + (b << 16);
    float Ia = im[iy0 * W + ix0], Ib = im[iy0 * W + ix1];
    float Ic = im[iy1 * W + ix0], Id = im[iy1 * W + ix1];
    float out = (1.f - wx) * (1.f - wy) * Ia + wx * (1.f - wy) * Ib
              + (1.f - wx) * wy * Ic + wx * wy * Id;
    img_next[tid] = out + zn * 0.001f;   // + z_next * MU^2 / L
}

extern "C" void kernel_launch(void* const* d_in, const int* in_sizes, int n_in,
                              void* d_out, int out_size, void* d_ws, size_t ws_size,
                              hipStream_t stream) {
    const float* source  = (const float*)d_in[0];
    const float* z0      = (const float*)d_in[1];
    const float* conv1_w = (const float*)d_in[2];
    const float* conv1_b = (const float*)d_in[3];
    const float* conv2_w = (const float*)d_in[4];

    float* out = (float*)d_out;
    float* images    = out;                              // [11][B][HW]
    float* fields    = images + (size_t)11 * B * HW;     // [10][B][HW][2]
    float* residuals = fields + (size_t)10 * B * HW * 2; // [11][B][HW]
    float* grads     = residuals + (size_t)11 * B * HW;  // [10][B][2][HW]

    float* ws = (float*)d_ws;
    float* t       = ws;                      // [B][2][HW]
    float* t2      = t + (size_t)B * 2 * HW;  // [B][2][HW]
    float* partial = t2 + (size_t)B * 2 * HW; // [NG][B][HW]
    float* gw      = partial + (size_t)NG * B * HW; // [51]

    init_kernel<<<B * HW / 256, 256, 0, stream>>>(source, z0, images, residuals, gw);

    for (int i = 0; i < LSTEPS; i++) {
        const float* img_i = images + (size_t)i * B * HW;
        const float* z_i   = residuals + (size_t)i * B * HW;
        float* fields_i    = fields + (size_t)i * B * HW * 2;

        grad_mul_kernel<<<B * HW / 256, 256, 0, stream>>>(img_i, z_i,
                grads + (size_t)i * B * 2 * HW, t);
        vblur_kernel<<<B * 2 * (W / VBC), 256, 0, stream>>>(t, gw, t2);
        hblur_kernel<<<B * H, 256, 0, stream>>>(t2, gw, fields_i);
        resblock_kernel<<<NG * B * 16, 256, 0, stream>>>(z_i, img_i,
                conv1_w + (size_t)i * NCH * 18, conv1_b + (size_t)i * NCH,
                conv2_w + (size_t)i * NCH * 9, partial);
        deform_kernel<<<B * HW / 256, 256, 0, stream>>>(img_i, z_i, fields_i, partial,
                residuals + (size_t)(i + 1) * B * HW, images + (size_t)(i + 1) * B * HW);
    }
}

// Round 2
// 763.749 us; speedup vs baseline: 1.2966x; 1.2966x over previous
//
#include <hip/hip_runtime.h>
#include <math.h>

#define B 4
#define H 256
#define W 256
#define HW 65536
#define LSTEPS 10
#define NCH 100
#define NG 8          // channel groups for resblock
#define KS 51
#define KR 25

// ---------------- init: copy source->images[0], broadcast z0->residuals[0], gauss weights
__global__ void init_kernel(const float* __restrict__ src, const float* __restrict__ z0,
                            float* __restrict__ images0, float* __restrict__ res0,
                            float* __restrict__ gw) {
    int tid = blockIdx.x * 256 + threadIdx.x;   // 0 .. B*HW-1
    images0[tid] = src[tid];
    res0[tid] = z0[tid & (HW - 1)];
    if (blockIdx.x == 0 && threadIdx.x == 0) {
        float e[KS];
        float s = 0.f;
        for (int k = 0; k < KS; k++) {
            float x = (float)(k - KR) / 6.0f;
            e[k] = expf(-0.5f * x * x);
            s += e[k];
        }
        for (int k = 0; k < KS; k++) gw[k] = e[k] / s;
    }
}

// ---------------- sobel gradient (edge clamp) + write grads + t = -z*g
__global__ void grad_mul_kernel(const float* __restrict__ img, const float* __restrict__ z,
                                float* __restrict__ grads_i, float* __restrict__ t) {
    int tid = blockIdx.x * 256 + threadIdx.x;   // 0 .. B*HW-1
    int b = tid >> 16;
    int p = tid & (HW - 1);
    int y = p >> 8, x = p & 255;
    const float* im = img + (b << 16);
    int ym = max(y - 1, 0), yp = min(y + 1, 255);
    int xm = max(x - 1, 0), xp = min(x + 1, 255);
    float a00 = im[ym * W + xm], a01 = im[ym * W + x], a02 = im[ym * W + xp];
    float a10 = im[y * W + xm],                         a12 = im[y * W + xp];
    float a20 = im[yp * W + xm], a21 = im[yp * W + x], a22 = im[yp * W + xp];
    float gx = ((a02 + 2.f * a12 + a22) - (a00 + 2.f * a10 + a20)) * 0.125f;
    float gy = ((a20 + 2.f * a21 + a22) - (a00 + 2.f * a01 + a02)) * 0.125f;
    grads_i[(b * 2 + 0) * HW + p] = gx;
    grads_i[(b * 2 + 1) * HW + p] = gy;
    float zz = z[tid];
    t[(b * 2 + 0) * HW + p] = -zz * gx;
    t[(b * 2 + 1) * HW + p] = -zz * gy;
}

// ---------------- vertical 51-tap blur (zero pad), 2D tiled for occupancy
// grid: (B*2) * (W/32) * (H/32) = 512 blocks, 256 threads; 32x32 outputs per block
#define VBC 32
#define VRT 32
__global__ void vblur_kernel(const float* __restrict__ t, const float* __restrict__ gw,
                             float* __restrict__ t2) {
    int bid = blockIdx.x;
    int rt = bid & 7;            // H/VRT
    int ct = (bid >> 3) & 7;     // W/VBC
    int bc = bid >> 6;           // b*2+ch
    int row0 = rt * VRT, col0 = ct * VBC;
    __shared__ float s[(VRT + 2 * KR) * VBC];    // 82*32 floats
    const float* src = t + bc * HW + col0;
    for (int idx = threadIdx.x; idx < (VRT + 2 * KR) * VBC; idx += 256) {
        int r = idx >> 5, c = idx & 31;
        int row = row0 + r - KR;
        s[idx] = ((unsigned)row < (unsigned)H) ? src[row * W + c] : 0.f;
    }
    __syncthreads();
    int c = threadIdx.x & 31;
    int rbase = (threadIdx.x >> 5) * 4;          // 8 groups of 4 rows
    float* dst = t2 + bc * HW + col0;
#pragma unroll
    for (int j = 0; j < 4; j++) {
        int row = rbase + j;
        float acc = 0.f;
#pragma unroll
        for (int k = 0; k < KS; k++) acc += gw[k] * s[(row + k) * VBC + c];
        dst[(row0 + row) * W + c] = acc;
    }
}

// ---------------- horizontal 51-tap blur + fields write + resblock-finalize + deform
// grid: B*H blocks, 256 threads (one row per block, one pixel per thread)
__global__ void hblur_deform_kernel(const float* __restrict__ t2, const float* __restrict__ gw,
                                    float* __restrict__ fields_i,
                                    const float* __restrict__ img, const float* __restrict__ z,
                                    const float* __restrict__ partial,
                                    float* __restrict__ res_next, float* __restrict__ img_next) {
    int b = blockIdx.x >> 8;
    int row = blockIdx.x & 255;
    __shared__ float s0[W + 2 * KR], s1[W + 2 * KR];
    const float* r0 = t2 + (b * 2 + 0) * HW + row * W;
    const float* r1 = t2 + (b * 2 + 1) * HW + row * W;
    for (int idx = threadIdx.x; idx < W + 2 * KR; idx += 256) {
        int xx = idx - KR;
        bool ok = (xx >= 0 && xx < W);
        s0[idx] = ok ? r0[xx] : 0.f;
        s1[idx] = ok ? r1[xx] : 0.f;
    }
    __syncthreads();
    int x = threadIdx.x;
    float a0 = 0.f, a1 = 0.f;
#pragma unroll
    for (int k = 0; k < KS; k++) {
        float wk = gw[k];
        a0 += wk * s0[x + k];
        a1 += wk * s1[x + k];
    }
    int p = row * W + x;
    int tid = (b << 16) + p;
    float2* fdst = (float2*)(fields_i + (size_t)tid * 2);
    *fdst = make_float2(a0, a1);

    // resblock finalize: sum channel-group partials -> z_next
    float f = 0.f;
#pragma unroll
    for (int g = 0; g < NG; g++) f += partial[(size_t)(g * B + b) * HW + p];
    float zn = z[tid] + f / 10.0f;
    res_next[tid] = zn;

    // bilinear deform
    float sx = (float)x - a0 / 10.0f;
    float sy = (float)row - a1 / 10.0f;
    float x0f = floorf(sx), y0f = floorf(sy);
    float wx = sx - x0f, wy = sy - y0f;
    int ix0 = min(max((int)x0f, 0), W - 1);
    int ix1 = min(max((int)x0f + 1, 0), W - 1);
    int iy0 = min(max((int)y0f, 0), H - 1);
    int iy1 = min(max((int)y0f + 1, 0), H - 1);
    const float* im = img + (b << 16);
    float Ia = im[iy0 * W + ix0], Ib = im[iy0 * W + ix1];
    float Ic = im[iy1 * W + ix0], Id = im[iy1 * W + ix1];
    float out = (1.f - wx) * (1.f - wy) * Ia + wx * (1.f - wy) * Ib
              + (1.f - wx) * wy * Ic + wx * wy * Id;
    img_next[tid] = out + zn * 0.001f;   // + z_next * MU^2 / L
}

// ---------------- fused resblock: conv3x3(2->100)+leaky+conv3x3(100->1), partial over channel group
// grid: NG*B*16 blocks, 256 threads; per-thread 4x4 outputs, 64x64 tile per block
__global__ __launch_bounds__(256, 1) void resblock_kernel(
        const float* __restrict__ z, const float* __restrict__ img,
        const float* __restrict__ w1, const float* __restrict__ b1,
        const float* __restrict__ w2, float* __restrict__ partial) {
    int bid = blockIdx.x;
    int tile = bid & 15;
    int b = (bid >> 4) & 3;
    int g = bid >> 6;
    int tx = tile & 3, ty = tile >> 2;
    int tid = threadIdx.x;
    int tcol = tid & 15, trow = tid >> 4;
    int ox = tx * 64 + tcol * 4;
    int oy = ty * 64 + trow * 4;
    const float* zp = z + (b << 16);
    const float* ip = img + (b << 16);

    // 8x8x2 input patch in registers, zero outside image (conv1 zero-pad)
    float inz[8][8], ini[8][8];
#pragma unroll
    for (int r = 0; r < 8; r++) {
        int y = oy - 2 + r;
        bool yok = ((unsigned)y < (unsigned)H);
#pragma unroll
        for (int c = 0; c < 8; c++) {
            int x = ox - 2 + c;
            bool ok = yok && ((unsigned)x < (unsigned)W);
            int idx = y * W + x;
            inz[r][c] = ok ? zp[idx] : 0.f;
            ini[r][c] = ok ? ip[idx] : 0.f;
        }
    }
    // hidden-position validity masks (conv2 sees ZERO outside [0,255], not conv1(bias))
    float mrow[6], mcol[6];
#pragma unroll
    for (int k = 0; k < 6; k++) {
        mrow[k] = ((unsigned)(oy - 1 + k) < (unsigned)H) ? 1.f : 0.f;
        mcol[k] = ((unsigned)(ox - 1 + k) < (unsigned)W) ? 1.f : 0.f;
    }

    float acc[4][4];
#pragma unroll
    for (int p = 0; p < 4; p++)
#pragma unroll
        for (int q = 0; q < 4; q++) acc[p][q] = 0.f;

    int c0 = (g < 4) ? g * 13 : 52 + (g - 4) * 12;
    int c1 = (g < 4) ? c0 + 13 : c0 + 12;

    for (int c = c0; c < c1; c++) {
        const float* w1c = w1 + c * 18;
        const float* w2c = w2 + c * 9;
        float bias = b1[c];
        float wz[9], wi[9], v2[9];
#pragma unroll
        for (int k = 0; k < 9; k++) {
            wz[k] = w1c[k];
            wi[k] = w1c[9 + k];
            v2[k] = w2c[k];
        }
        float h[6][6];
#pragma unroll
        for (int hr = 0; hr < 6; hr++) {
#pragma unroll
            for (int hc = 0; hc < 6; hc++) {
                float a = bias;
#pragma unroll
                for (int ky = 0; ky < 3; ky++) {
#pragma unroll
                    for (int kx = 0; kx < 3; kx++) {
                        a += wz[ky * 3 + kx] * inz[hr + ky][hc + kx];
                        a += wi[ky * 3 + kx] * ini[hr + ky][hc + kx];
                    }
                }
                float l = fmaxf(a, 0.01f * a);        // leaky relu (slope<1)
                h[hr][hc] = l * mrow[hr] * mcol[hc];  // mask invalid hidden positions
            }
        }
#pragma unroll
        for (int p = 0; p < 4; p++) {
#pragma unroll
            for (int q = 0; q < 4; q++) {
                float a = acc[p][q];
#pragma unroll
                for (int ky = 0; ky < 3; ky++) {
#pragma unroll
                    for (int kx = 0; kx < 3; kx++)
                        a += v2[ky * 3 + kx] * h[p + ky][q + kx];
                }
                acc[p][q] = a;
            }
        }
    }
    float* dst = partial + (size_t)(g * B + b) * HW;
#pragma unroll
    for (int p = 0; p < 4; p++)
#pragma unroll
        for (int q = 0; q < 4; q++)
            dst[(oy + p) * W + ox + q] = acc[p][q];
}

extern "C" void kernel_launch(void* const* d_in, const int* in_sizes, int n_in,
                              void* d_out, int out_size, void* d_ws, size_t ws_size,
                              hipStream_t stream) {
    const float* source  = (const float*)d_in[0];
    const float* z0      = (const float*)d_in[1];
    const float* conv1_w = (const float*)d_in[2];
    const float* conv1_b = (const float*)d_in[3];
    const float* conv2_w = (const float*)d_in[4];

    float* out = (float*)d_out;
    float* images    = out;                              // [11][B][HW]
    float* fields    = images + (size_t)11 * B * HW;     // [10][B][HW][2]
    float* residuals = fields + (size_t)10 * B * HW * 2; // [11][B][HW]
    float* grads     = residuals + (size_t)11 * B * HW;  // [10][B][2][HW]

    float* ws = (float*)d_ws;
    float* t       = ws;                      // [B][2][HW]
    float* t2      = t + (size_t)B * 2 * HW;  // [B][2][HW]
    float* partial = t2 + (size_t)B * 2 * HW; // [NG][B][HW]
    float* gw      = partial + (size_t)NG * B * HW; // [51]

    init_kernel<<<B * HW / 256, 256, 0, stream>>>(source, z0, images, residuals, gw);

    for (int i = 0; i < LSTEPS; i++) {
        const float* img_i = images + (size_t)i * B * HW;
        const float* z_i   = residuals + (size_t)i * B * HW;
        float* fields_i    = fields + (size_t)i * B * HW * 2;

        grad_mul_kernel<<<B * HW / 256, 256, 0, stream>>>(img_i, z_i,
                grads + (size_t)i * B * 2 * HW, t);
        vblur_kernel<<<B * 2 * (W / VBC) * (H / VRT), 256, 0, stream>>>(t, gw, t2);
        resblock_kernel<<<NG * B * 16, 256, 0, stream>>>(z_i, img_i,
                conv1_w + (size_t)i * NCH * 18, conv1_b + (size_t)i * NCH,
                conv2_w + (size_t)i * NCH * 9, partial);
        hblur_deform_kernel<<<B * H, 256, 0, stream>>>(t2, gw, fields_i,
                img_i, z_i, partial,
                residuals + (size_t)(i + 1) * B * HW, images + (size_t)(i + 1) * B * HW);
    }
}

// Round 3
// 447.053 us; speedup vs baseline: 2.2152x; 1.7084x over previous
//
#include <hip/hip_runtime.h>
#include <hip/hip_bf16.h>
#include <math.h>

#define B 4
#define H 256
#define W 256
#define HW 65536
#define LSTEPS 10
#define NCH 100
#define KS 51
#define KR 25

// ---------------- init: copy source->images[0], broadcast z0->residuals[0], gauss weights
__global__ void init_kernel(const float* __restrict__ src, const float* __restrict__ z0,
                            float* __restrict__ images0, float* __restrict__ res0,
                            float* __restrict__ gw) {
    int tid = blockIdx.x * 256 + threadIdx.x;   // 0 .. B*HW-1
    images0[tid] = src[tid];
    res0[tid] = z0[tid & (HW - 1)];
    if (blockIdx.x == 0 && threadIdx.x == 0) {
        float e[KS];
        float s = 0.f;
        for (int k = 0; k < KS; k++) {
            float x = (float)(k - KR) / 6.0f;
            e[k] = expf(-0.5f * x * x);
            s += e[k];
        }
        for (int k = 0; k < KS; k++) gw[k] = e[k] / s;
    }
}

// ---------------- sobel gradient (edge clamp) + write grads + t = -z*g
__global__ void grad_mul_kernel(const float* __restrict__ img, const float* __restrict__ z,
                                float* __restrict__ grads_i, float* __restrict__ t) {
    int tid = blockIdx.x * 256 + threadIdx.x;   // 0 .. B*HW-1
    int b = tid >> 16;
    int p = tid & (HW - 1);
    int y = p >> 8, x = p & 255;
    const float* im = img + (b << 16);
    int ym = max(y - 1, 0), yp = min(y + 1, 255);
    int xm = max(x - 1, 0), xp = min(x + 1, 255);
    float a00 = im[ym * W + xm], a01 = im[ym * W + x], a02 = im[ym * W + xp];
    float a10 = im[y * W + xm],                         a12 = im[y * W + xp];
    float a20 = im[yp * W + xm], a21 = im[yp * W + x], a22 = im[yp * W + xp];
    float gx = ((a02 + 2.f * a12 + a22) - (a00 + 2.f * a10 + a20)) * 0.125f;
    float gy = ((a20 + 2.f * a21 + a22) - (a00 + 2.f * a01 + a02)) * 0.125f;
    grads_i[(b * 2 + 0) * HW + p] = gx;
    grads_i[(b * 2 + 1) * HW + p] = gy;
    float zz = z[tid];
    t[(b * 2 + 0) * HW + p] = -zz * gx;
    t[(b * 2 + 1) * HW + p] = -zz * gy;
}

// ---------------- vertical 51-tap blur (zero pad), 2D tiled for occupancy
// grid: (B*2) * (W/32) * (H/32) = 512 blocks, 256 threads; 32x32 outputs per block
#define VBC 32
#define VRT 32
__global__ void vblur_kernel(const float* __restrict__ t, const float* __restrict__ gw,
                             float* __restrict__ t2) {
    int bid = blockIdx.x;
    int rt = bid & 7;            // H/VRT
    int ct = (bid >> 3) & 7;     // W/VBC
    int bc = bid >> 6;           // b*2+ch
    int row0 = rt * VRT, col0 = ct * VBC;
    __shared__ float s[(VRT + 2 * KR) * VBC];    // 82*32 floats
    const float* src = t + bc * HW + col0;
    for (int idx = threadIdx.x; idx < (VRT + 2 * KR) * VBC; idx += 256) {
        int r = idx >> 5, c = idx & 31;
        int row = row0 + r - KR;
        s[idx] = ((unsigned)row < (unsigned)H) ? src[row * W + c] : 0.f;
    }
    __syncthreads();
    int c = threadIdx.x & 31;
    int rbase = (threadIdx.x >> 5) * 4;          // 8 groups of 4 rows
    float* dst = t2 + bc * HW + col0;
#pragma unroll
    for (int j = 0; j < 4; j++) {
        int row = rbase + j;
        float acc = 0.f;
#pragma unroll
        for (int k = 0; k < KS; k++) acc += gw[k] * s[(row + k) * VBC + c];
        dst[(row0 + row) * W + c] = acc;
    }
}

// ---------------- S-map resblock: per pixel, all 100 channels, zero redundancy.
// S_t[p] = sum_c v2[c][t] * leaky(conv1_c(p)); out[p] = sum_t S_t[p+delta_t] (pass 2).
// grid: B*HW/256 = 1024 blocks, 256 threads, 1 pixel/thread.
__global__ __launch_bounds__(256) void smap_kernel(
        const float* __restrict__ z, const float* __restrict__ img,
        const float* __restrict__ w1, const float* __restrict__ b1,
        const float* __restrict__ w2, __hip_bfloat16* __restrict__ S) {
    int tid = blockIdx.x * 256 + threadIdx.x;   // 0 .. B*HW-1
    int b = tid >> 16;
    int p = tid & (HW - 1);
    int y = p >> 8, x = p & 255;
    const float* zp = z + (b << 16);
    const float* ip = img + (b << 16);

    // 3x3x2 input patch (zero outside image); always-in-bounds load + select
    float pz[9], pi[9];
#pragma unroll
    for (int dy = -1; dy <= 1; dy++) {
#pragma unroll
        for (int dx = -1; dx <= 1; dx++) {
            int yy = y + dy, xx = x + dx;
            bool ok = ((unsigned)yy < (unsigned)H) && ((unsigned)xx < (unsigned)W);
            int idx = ok ? (yy * W + xx) : 0;
            int k = (dy + 1) * 3 + (dx + 1);
            float vz = zp[idx], vi = ip[idx];
            pz[k] = ok ? vz : 0.f;
            pi[k] = ok ? vi : 0.f;
        }
    }

    float s[9];
#pragma unroll
    for (int t = 0; t < 9; t++) s[t] = 0.f;

#pragma unroll 4
    for (int c = 0; c < NCH; c++) {
        const float* w1c = w1 + c * 18;          // uniform -> s_load
        const float* v2c = w2 + c * 9;
        float hz = b1[c];                         // bias seeds chain 1
        float hi = 0.f;
#pragma unroll
        for (int k = 0; k < 9; k++) {
            hz = fmaf(w1c[k], pz[k], hz);
            hi = fmaf(w1c[9 + k], pi[k], hi);
        }
        float a = hz + hi;
        float h = fmaxf(a, 0.01f * a);            // leaky relu
#pragma unroll
        for (int t = 0; t < 9; t++) s[t] = fmaf(v2c[t], h, s[t]);
    }

#pragma unroll
    for (int t = 0; t < 9; t++)
        S[(size_t)t * (B * HW) + tid] = __float2bfloat16(s[t]);
}

// ---------------- horizontal 51-tap blur + fields write + S-gather (conv2 finish) + deform
// grid: B*H blocks, 256 threads (one row per block, one pixel per thread)
__global__ void hblur_deform_kernel(const float* __restrict__ t2, const float* __restrict__ gw,
                                    float* __restrict__ fields_i,
                                    const float* __restrict__ img, const float* __restrict__ z,
                                    const __hip_bfloat16* __restrict__ S,
                                    float* __restrict__ res_next, float* __restrict__ img_next) {
    int b = blockIdx.x >> 8;
    int row = blockIdx.x & 255;
    __shared__ float s0[W + 2 * KR], s1[W + 2 * KR];
    const float* r0 = t2 + (b * 2 + 0) * HW + row * W;
    const float* r1 = t2 + (b * 2 + 1) * HW + row * W;
    for (int idx = threadIdx.x; idx < W + 2 * KR; idx += 256) {
        int xx = idx - KR;
        bool ok = (xx >= 0 && xx < W);
        s0[idx] = ok ? r0[xx] : 0.f;
        s1[idx] = ok ? r1[xx] : 0.f;
    }
    __syncthreads();
    int x = threadIdx.x;
    float a0 = 0.f, a1 = 0.f;
#pragma unroll
    for (int k = 0; k < KS; k++) {
        float wk = gw[k];
        a0 += wk * s0[x + k];
        a1 += wk * s1[x + k];
    }
    int p = row * W + x;
    int tid = (b << 16) + p;
    float2* fdst = (float2*)(fields_i + (size_t)tid * 2);
    *fdst = make_float2(a0, a1);

    // conv2 finish: out[y,x] = sum_t S_t[y-1+ty, x-1+tx], S == 0 outside image
    float f = 0.f;
#pragma unroll
    for (int t = 0; t < 9; t++) {
        int yy = row - 1 + t / 3;
        int xx = x - 1 + t % 3;
        if (((unsigned)yy < (unsigned)H) && ((unsigned)xx < (unsigned)W))
            f += __bfloat162float(S[(size_t)t * (B * HW) + (b << 16) + yy * W + xx]);
    }
    float zn = z[tid] + f / 10.0f;
    res_next[tid] = zn;

    // bilinear deform
    float sx = (float)x - a0 / 10.0f;
    float sy = (float)row - a1 / 10.0f;
    float x0f = floorf(sx), y0f = floorf(sy);
    float wx = sx - x0f, wy = sy - y0f;
    int ix0 = min(max((int)x0f, 0), W - 1);
    int ix1 = min(max((int)x0f + 1, 0), W - 1);
    int iy0 = min(max((int)y0f, 0), H - 1);
    int iy1 = min(max((int)y0f + 1, 0), H - 1);
    const float* im = img + (b << 16);
    float Ia = im[iy0 * W + ix0], Ib = im[iy0 * W + ix1];
    float Ic = im[iy1 * W + ix0], Id = im[iy1 * W + ix1];
    float out = (1.f - wx) * (1.f - wy) * Ia + wx * (1.f - wy) * Ib
              + (1.f - wx) * wy * Ic + wx * wy * Id;
    img_next[tid] = out + zn * 0.001f;   // + z_next * MU^2 / L
}

extern "C" void kernel_launch(void* const* d_in, const int* in_sizes, int n_in,
                              void* d_out, int out_size, void* d_ws, size_t ws_size,
                              hipStream_t stream) {
    const float* source  = (const float*)d_in[0];
    const float* z0      = (const float*)d_in[1];
    const float* conv1_w = (const float*)d_in[2];
    const float* conv1_b = (const float*)d_in[3];
    const float* conv2_w = (const float*)d_in[4];

    float* out = (float*)d_out;
    float* images    = out;                              // [11][B][HW]
    float* fields    = images + (size_t)11 * B * HW;     // [10][B][HW][2]
    float* residuals = fields + (size_t)10 * B * HW * 2; // [11][B][HW]
    float* grads     = residuals + (size_t)11 * B * HW;  // [10][B][2][HW]

    float* ws = (float*)d_ws;
    float* t  = ws;                           // [B][2][HW] f32
    float* t2 = t + (size_t)B * 2 * HW;       // [B][2][HW] f32
    __hip_bfloat16* S = (__hip_bfloat16*)(t2 + (size_t)B * 2 * HW);  // [9][B][HW] bf16
    float* gw = (float*)(S + (size_t)9 * B * HW);                    // [51]

    init_kernel<<<B * HW / 256, 256, 0, stream>>>(source, z0, images, residuals, gw);

    for (int i = 0; i < LSTEPS; i++) {
        const float* img_i = images + (size_t)i * B * HW;
        const float* z_i   = residuals + (size_t)i * B * HW;
        float* fields_i    = fields + (size_t)i * B * HW * 2;

        grad_mul_kernel<<<B * HW / 256, 256, 0, stream>>>(img_i, z_i,
                grads + (size_t)i * B * 2 * HW, t);
        vblur_kernel<<<B * 2 * (W / VBC) * (H / VRT), 256, 0, stream>>>(t, gw, t2);
        smap_kernel<<<B * HW / 256, 256, 0, stream>>>(z_i, img_i,
                conv1_w + (size_t)i * NCH * 18, conv1_b + (size_t)i * NCH,
                conv2_w + (size_t)i * NCH * 9, S);
        hblur_deform_kernel<<<B * H, 256, 0, stream>>>(t2, gw, fields_i,
                img_i, z_i, S,
                residuals + (size_t)(i + 1) * B * HW, images + (size_t)(i + 1) * B * HW);
    }
}

// Round 4
// 420.180 us; speedup vs baseline: 2.3568x; 1.0640x over previous
//
#include <hip/hip_runtime.h>
#include <hip/hip_bf16.h>
#include <math.h>

#define B 4
#define H 256
#define W 256
#define HW 65536
#define LSTEPS 10
#define NCH 100
#define KS 51
#define KR 25

// ---------------- init: copy source->images[0], broadcast z0->residuals[0], gauss weights
__global__ void init_kernel(const float* __restrict__ src, const float* __restrict__ z0,
                            float* __restrict__ images0, float* __restrict__ res0,
                            float* __restrict__ gw) {
    int tid = blockIdx.x * 256 + threadIdx.x;   // 0 .. B*HW-1
    images0[tid] = src[tid];
    res0[tid] = z0[tid & (HW - 1)];
    if (blockIdx.x == 0 && threadIdx.x == 0) {
        float e[KS];
        float s = 0.f;
        for (int k = 0; k < KS; k++) {
            float x = (float)(k - KR) / 6.0f;
            e[k] = expf(-0.5f * x * x);
            s += e[k];
        }
        for (int k = 0; k < KS; k++) gw[k] = e[k] / s;
    }
}

// ---------------- weight repack: per (step,channel) 32-float record
// [0..8]=w1 z-chan, [9..17]=w1 img-chan, [18..26]=conv2, [27]=bias, [28..31]=0
__global__ void wrepack_kernel(const float* __restrict__ conv1_w, const float* __restrict__ conv1_b,
                               const float* __restrict__ conv2_w, float* __restrict__ wpack) {
    int idx = blockIdx.x * 256 + threadIdx.x;   // 0 .. LSTEPS*NCH-1
    if (idx >= LSTEPS * NCH) return;
    int i = idx / NCH, c = idx % NCH;
    float* dst = wpack + (size_t)idx * 32;
    const float* w1c = conv1_w + (size_t)i * NCH * 18 + c * 18;
    const float* w2c = conv2_w + (size_t)i * NCH * 9 + c * 9;
#pragma unroll
    for (int k = 0; k < 18; k++) dst[k] = w1c[k];
#pragma unroll
    for (int k = 0; k < 9; k++) dst[18 + k] = w2c[k];
    dst[27] = conv1_b[(size_t)i * NCH + c];
    dst[28] = 0.f; dst[29] = 0.f; dst[30] = 0.f; dst[31] = 0.f;
}

// ---------------- fused: sobel grad (+grads, t writes) + S-map resblock (zero redundancy)
// grid: B*HW/256 = 1024 blocks, 256 threads, 1 pixel/thread.
__global__ __launch_bounds__(256) void grad_smap_kernel(
        const float* __restrict__ z, const float* __restrict__ img,
        const float* __restrict__ wp, __hip_bfloat16* __restrict__ S,
        float* __restrict__ grads_i, float* __restrict__ t) {
    int tid = blockIdx.x * 256 + threadIdx.x;   // 0 .. B*HW-1
    int b = tid >> 16;
    int p = tid & (HW - 1);
    int y = p >> 8, x = p & 255;
    const float* zp = z + (b << 16);
    const float* ip = img + (b << 16);

    // clamped-index loads (always valid) -> raw values for Sobel (edge-pad),
    // zeroed copies for conv (zero-pad)
    float rz[9], ri[9], pz[9], pi[9];
#pragma unroll
    for (int dy = -1; dy <= 1; dy++) {
#pragma unroll
        for (int dx = -1; dx <= 1; dx++) {
            int yy = y + dy, xx = x + dx;
            bool ok = ((unsigned)yy < (unsigned)H) && ((unsigned)xx < (unsigned)W);
            int yc = min(max(yy, 0), H - 1);
            int xc = min(max(xx, 0), W - 1);
            int k = (dy + 1) * 3 + (dx + 1);
            float vz = zp[yc * W + xc], vi = ip[yc * W + xc];
            rz[k] = vz; ri[k] = vi;
            pz[k] = ok ? vz : 0.f;
            pi[k] = ok ? vi : 0.f;
        }
    }

    // Sobel on edge-clamped img values
    float gx = ((ri[2] + 2.f * ri[5] + ri[8]) - (ri[0] + 2.f * ri[3] + ri[6])) * 0.125f;
    float gy = ((ri[6] + 2.f * ri[7] + ri[8]) - (ri[0] + 2.f * ri[1] + ri[2])) * 0.125f;
    grads_i[(b * 2 + 0) * HW + p] = gx;
    grads_i[(b * 2 + 1) * HW + p] = gy;
    float zc = rz[4];
    t[(b * 2 + 0) * HW + p] = -zc * gx;
    t[(b * 2 + 1) * HW + p] = -zc * gy;

    // S-map: S_t[p] = sum_c v2[c][t] * leaky(conv1_c(p))
    float s[9];
#pragma unroll
    for (int q = 0; q < 9; q++) s[q] = 0.f;

#pragma unroll 2
    for (int c = 0; c < NCH; c++) {
        const float* wc = wp + c * 32;            // uniform -> s_load_dwordx16 x2
        float hz = wc[27];
        float hi = 0.f;
#pragma unroll
        for (int k = 0; k < 9; k++) {
            hz = fmaf(wc[k], pz[k], hz);
            hi = fmaf(wc[9 + k], pi[k], hi);
        }
        float a = hz + hi;
        float h = fmaxf(a, 0.01f * a);            // leaky relu
#pragma unroll
        for (int q = 0; q < 9; q++) s[q] = fmaf(wc[18 + q], h, s[q]);
    }

#pragma unroll
    for (int q = 0; q < 9; q++)
        S[(size_t)q * (B * HW) + tid] = __float2bfloat16(s[q]);
}

// ---------------- vertical 51-tap blur (zero pad), 2D tiled
// grid: (B*2) * (W/32) * (H/32) = 512 blocks, 256 threads; 32x32 outputs per block
#define VBC 32
#define VRT 32
__global__ void vblur_kernel(const float* __restrict__ t, const float* __restrict__ gw,
                             float* __restrict__ t2) {
    int bid = blockIdx.x;
    int rt = bid & 7;            // H/VRT
    int ct = (bid >> 3) & 7;     // W/VBC
    int bc = bid >> 6;           // b*2+ch
    int row0 = rt * VRT, col0 = ct * VBC;
    __shared__ float s[(VRT + 2 * KR) * VBC];    // 82*32 floats
    const float* src = t + bc * HW + col0;
    for (int idx = threadIdx.x; idx < (VRT + 2 * KR) * VBC; idx += 256) {
        int r = idx >> 5, c = idx & 31;
        int row = row0 + r - KR;
        s[idx] = ((unsigned)row < (unsigned)H) ? src[row * W + c] : 0.f;
    }
    __syncthreads();
    int c = threadIdx.x & 31;
    int rbase = (threadIdx.x >> 5) * 4;          // 8 groups of 4 rows
    float* dst = t2 + bc * HW + col0;
#pragma unroll
    for (int j = 0; j < 4; j++) {
        int row = rbase + j;
        float acc = 0.f;
#pragma unroll
        for (int k = 0; k < KS; k++) acc += gw[k] * s[(row + k) * VBC + c];
        dst[(row0 + row) * W + c] = acc;
    }
}

// ---------------- horizontal 51-tap blur + fields write + S-gather (conv2 finish) + deform
// grid: B*H blocks, 256 threads (one row per block, one pixel per thread)
__global__ void hblur_deform_kernel(const float* __restrict__ t2, const float* __restrict__ gw,
                                    float* __restrict__ fields_i,
                                    const float* __restrict__ img, const float* __restrict__ z,
                                    const __hip_bfloat16* __restrict__ S,
                                    float* __restrict__ res_next, float* __restrict__ img_next) {
    int b = blockIdx.x >> 8;
    int row = blockIdx.x & 255;
    __shared__ float s0[W + 2 * KR], s1[W + 2 * KR];
    const float* r0 = t2 + (b * 2 + 0) * HW + row * W;
    const float* r1 = t2 + (b * 2 + 1) * HW + row * W;
    for (int idx = threadIdx.x; idx < W + 2 * KR; idx += 256) {
        int xx = idx - KR;
        bool ok = (xx >= 0 && xx < W);
        s0[idx] = ok ? r0[xx] : 0.f;
        s1[idx] = ok ? r1[xx] : 0.f;
    }
    __syncthreads();
    int x = threadIdx.x;
    float a0 = 0.f, a1 = 0.f;
#pragma unroll
    for (int k = 0; k < KS; k++) {
        float wk = gw[k];
        a0 += wk * s0[x + k];
        a1 += wk * s1[x + k];
    }
    int p = row * W + x;
    int tid = (b << 16) + p;
    float2* fdst = (float2*)(fields_i + (size_t)tid * 2);
    *fdst = make_float2(a0, a1);

    // conv2 finish: out[y,x] = sum_t S_t[y-1+ty, x-1+tx], S == 0 outside image
    float f = 0.f;
#pragma unroll
    for (int q = 0; q < 9; q++) {
        int yy = row - 1 + q / 3;
        int xx = x - 1 + q % 3;
        if (((unsigned)yy < (unsigned)H) && ((unsigned)xx < (unsigned)W))
            f += __bfloat162float(S[(size_t)q * (B * HW) + (b << 16) + yy * W + xx]);
    }
    float zn = z[tid] + f / 10.0f;
    res_next[tid] = zn;

    // bilinear deform
    float sx = (float)x - a0 / 10.0f;
    float sy = (float)row - a1 / 10.0f;
    float x0f = floorf(sx), y0f = floorf(sy);
    float wx = sx - x0f, wy = sy - y0f;
    int ix0 = min(max((int)x0f, 0), W - 1);
    int ix1 = min(max((int)x0f + 1, 0), W - 1);
    int iy0 = min(max((int)y0f, 0), H - 1);
    int iy1 = min(max((int)y0f + 1, 0), H - 1);
    const float* im = img + (b << 16);
    float Ia = im[iy0 * W + ix0], Ib = im[iy0 * W + ix1];
    float Ic = im[iy1 * W + ix0], Id = im[iy1 * W + ix1];
    float out = (1.f - wx) * (1.f - wy) * Ia + wx * (1.f - wy) * Ib
              + (1.f - wx) * wy * Ic + wx * wy * Id;
    img_next[tid] = out + zn * 0.001f;   // + z_next * MU^2 / L
}

extern "C" void kernel_launch(void* const* d_in, const int* in_sizes, int n_in,
                              void* d_out, int out_size, void* d_ws, size_t ws_size,
                              hipStream_t stream) {
    const float* source  = (const float*)d_in[0];
    const float* z0      = (const float*)d_in[1];
    const float* conv1_w = (const float*)d_in[2];
    const float* conv1_b = (const float*)d_in[3];
    const float* conv2_w = (const float*)d_in[4];

    float* out = (float*)d_out;
    float* images    = out;                              // [11][B][HW]
    float* fields    = images + (size_t)11 * B * HW;     // [10][B][HW][2]
    float* residuals = fields + (size_t)10 * B * HW * 2; // [11][B][HW]
    float* grads     = residuals + (size_t)11 * B * HW;  // [10][B][2][HW]

    float* ws = (float*)d_ws;
    float* t  = ws;                           // [B][2][HW] f32
    float* t2 = t + (size_t)B * 2 * HW;       // [B][2][HW] f32
    __hip_bfloat16* S = (__hip_bfloat16*)(t2 + (size_t)B * 2 * HW);  // [9][B][HW] bf16
    float* gw = (float*)(S + (size_t)9 * B * HW);                    // [51]
    float* wpack = gw + 64;                   // [LSTEPS*NCH][32]

    init_kernel<<<B * HW / 256, 256, 0, stream>>>(source, z0, images, residuals, gw);
    wrepack_kernel<<<(LSTEPS * NCH + 255) / 256, 256, 0, stream>>>(conv1_w, conv1_b, conv2_w, wpack);

    for (int i = 0; i < LSTEPS; i++) {
        const float* img_i = images + (size_t)i * B * HW;
        const float* z_i   = residuals + (size_t)i * B * HW;
        float* fields_i    = fields + (size_t)i * B * HW * 2;

        grad_smap_kernel<<<B * HW / 256, 256, 0, stream>>>(z_i, img_i,
                wpack + (size_t)i * NCH * 32, S,
                grads + (size_t)i * B * 2 * HW, t);
        vblur_kernel<<<B * 2 * (W / VBC) * (H / VRT), 256, 0, stream>>>(t, gw, t2);
        hblur_deform_kernel<<<B * H, 256, 0, stream>>>(t2, gw, fields_i,
                img_i, z_i, S,
                residuals + (size_t)(i + 1) * B * HW, images + (size_t)(i + 1) * B * HW);
    }
}